// Round 2
// baseline (157.126 us; speedup 1.0000x reference)
//
#include <hip/hip_runtime.h>

// Problem constants (fixed by setup_inputs)
#define N_NODES 2048
#define N_GRAPHS 32
#define NPG 64
#define N_EDGES 16384
#define EPG 512          // edges per graph (graph-major ordering)
#define HIDDEN 256
#define NHEADS 8
#define HEADDIM 32
#define EDGEFEAT 16
#define ATT_SCALE 0.17677669529663687f  // 32^-0.5

// ---------------------------------------------------------------------------
// Tiled fp32 GEMM: C[M,N] = A[M,K] @ B[K,N] + bias[N].
// BM=BN=64, BK=16, 256 threads, 4x4 per thread, fp32 throughout.
// ---------------------------------------------------------------------------
__global__ __launch_bounds__(256)
void gemm_f32_kernel(const float* __restrict__ A, const float* __restrict__ B,
                     const float* __restrict__ bias, float* __restrict__ C,
                     int M, int N, int K)
{
    __shared__ float As[16][68];   // [k][m]; 68*4=272 B rows keep float4 align
    __shared__ float Bs[16][68];   // [k][n]
    const int tid = threadIdx.x;
    const int m0 = blockIdx.y * 64;
    const int n0 = blockIdx.x * 64;
    const int tx = tid & 15, ty = tid >> 4;
    float acc[4][4] = {};

    for (int k0 = 0; k0 < K; k0 += 16) {
        {   // A tile 64x16: one float4 per thread, store transposed
            const int r = tid >> 2, c = (tid & 3) * 4;
            float4 a4 = *(const float4*)(A + (size_t)(m0 + r) * K + k0 + c);
            As[c + 0][r] = a4.x;
            As[c + 1][r] = a4.y;
            As[c + 2][r] = a4.z;
            As[c + 3][r] = a4.w;
        }
        {   // B tile 16x64: one float4 per thread
            const int r = tid >> 4, c = (tid & 15) * 4;
            float4 b4 = *(const float4*)(B + (size_t)(k0 + r) * N + n0 + c);
            Bs[r][c + 0] = b4.x;
            Bs[r][c + 1] = b4.y;
            Bs[r][c + 2] = b4.z;
            Bs[r][c + 3] = b4.w;
        }
        __syncthreads();
        #pragma unroll
        for (int k = 0; k < 16; ++k) {
            float4 av = *(const float4*)&As[k][ty * 4];
            float4 bv = *(const float4*)&Bs[k][tx * 4];
            float a[4] = {av.x, av.y, av.z, av.w};
            float b[4] = {bv.x, bv.y, bv.z, bv.w};
            #pragma unroll
            for (int i = 0; i < 4; ++i)
                #pragma unroll
                for (int j = 0; j < 4; ++j)
                    acc[i][j] += a[i] * b[j];
        }
        __syncthreads();
    }

    float4 bsv = *(const float4*)(bias + n0 + tx * 4);
    #pragma unroll
    for (int i = 0; i < 4; ++i) {
        const int m = m0 + ty * 4 + i;
        float4 o;
        o.x = acc[i][0] + bsv.x;
        o.y = acc[i][1] + bsv.y;
        o.z = acc[i][2] + bsv.z;
        o.w = acc[i][3] + bsv.w;
        *(float4*)(C + (size_t)m * N + n0 + tx * 4) = o;
    }
}

// ---------------------------------------------------------------------------
// Fused block-diagonal attention, one block per (graph, head), fp32.
// Computes scores, inline edge-bias (edges@We[:,h] + be[h] scattered at
// (receiver, sender) — unique pairs per graph => race-free), softmax, AV.
// attn output overwrites the Q workspace slot: block (g,h) reads only
// rows g*64..g*64+63, cols h*32..h*32+31 of Q and writes the same slice,
// so cross-block slices are disjoint under any scheduling.
// ---------------------------------------------------------------------------
__global__ __launch_bounds__(256)
void attn_f32_kernel(const float* __restrict__ q,      // [2048][256]
                     const float* __restrict__ k,
                     const float* __restrict__ v,
                     const float* __restrict__ edges,  // [16384][16]
                     const float* __restrict__ We,     // [16][8]
                     const float* __restrict__ be,     // [8]
                     const int* __restrict__ senders,
                     const int* __restrict__ receivers,
                     float* __restrict__ attn_out)     // aliases q (safe, see above)
{
    const int g = blockIdx.x;   // graph 0..31
    const int h = blockIdx.y;   // head  0..7
    const int tid = threadIdx.x;

    __shared__ float qs[NPG][HEADDIM + 1];
    __shared__ float ks[NPG][HEADDIM + 1];
    __shared__ float vs[NPG][HEADDIM + 1];
    __shared__ float sc[NPG][NPG + 1];
    __shared__ float we_h[EDGEFEAT];
    __shared__ float sbe;

    if (tid < EDGEFEAT) we_h[tid] = We[tid * NHEADS + h];
    if (tid == 0) sbe = be[h];

    {   // load q,k,v head slices: 8 floats (2x float4) per thread per tensor
        const int row = tid >> 2;
        const int c8  = (tid & 3) * 8;
        const size_t base = (size_t)(g * NPG + row) * HIDDEN + h * HEADDIM + c8;
        float4 a0 = *(const float4*)(q + base);
        float4 a1 = *(const float4*)(q + base + 4);
        *(float4*)&qs[row][c8]     = a0;
        *(float4*)&qs[row][c8 + 4] = a1;
        float4 b0 = *(const float4*)(k + base);
        float4 b1 = *(const float4*)(k + base + 4);
        *(float4*)&ks[row][c8]     = b0;
        *(float4*)&ks[row][c8 + 4] = b1;
        float4 c0 = *(const float4*)(v + base);
        float4 c1 = *(const float4*)(v + base + 4);
        *(float4*)&vs[row][c8]     = c0;
        *(float4*)&vs[row][c8 + 4] = c1;
    }
    __syncthreads();

    {   // scores: thread (i = tid&63, jb = tid>>6) computes 16 j's
        const int i = tid & 63;
        const int jb = tid >> 6;
        float qr[HEADDIM];
        #pragma unroll
        for (int d = 0; d < HEADDIM; ++d) qr[d] = qs[i][d];
        #pragma unroll
        for (int jj = 0; jj < 16; ++jj) {
            const int j = jb * 16 + jj;
            float acc = 0.f;
            #pragma unroll
            for (int d = 0; d < HEADDIM; ++d) acc += qr[d] * ks[j][d];
            sc[i][j] = acc * ATT_SCALE;
        }
    }
    __syncthreads();

    {   // edge bias: 512 edges/graph, 2 per thread, unique (r,s) -> race-free
        #pragma unroll
        for (int rep = 0; rep < 2; ++rep) {
            const int e = g * EPG + rep * 256 + tid;
            const float* ef = edges + (size_t)e * EDGEFEAT;
            float4 f0 = *(const float4*)(ef + 0);
            float4 f1 = *(const float4*)(ef + 4);
            float4 f2 = *(const float4*)(ef + 8);
            float4 f3 = *(const float4*)(ef + 12);
            float b = sbe
                + f0.x * we_h[0]  + f0.y * we_h[1]  + f0.z * we_h[2]  + f0.w * we_h[3]
                + f1.x * we_h[4]  + f1.y * we_h[5]  + f1.z * we_h[6]  + f1.w * we_h[7]
                + f2.x * we_h[8]  + f2.y * we_h[9]  + f2.z * we_h[10] + f2.w * we_h[11]
                + f3.x * we_h[12] + f3.y * we_h[13] + f3.z * we_h[14] + f3.w * we_h[15];
            const int s_l = senders[e] & (NPG - 1);
            const int r_l = receivers[e] & (NPG - 1);
            sc[r_l][s_l] += b;
        }
    }
    __syncthreads();

    if (tid < NPG) {   // softmax over j (full 64 keys: block-diagonal graphs)
        const int i = tid;
        float m = -1e30f;
        #pragma unroll
        for (int j = 0; j < NPG; ++j) m = fmaxf(m, sc[i][j]);
        float sum = 0.f;
        #pragma unroll
        for (int j = 0; j < NPG; ++j) {
            float e = __expf(sc[i][j] - m);
            sc[i][j] = e;
            sum += e;
        }
        const float inv = 1.f / sum;
        #pragma unroll
        for (int j = 0; j < NPG; ++j) sc[i][j] *= inv;
    }
    __syncthreads();

    {   // out[i][d] = sum_j p[i][j] * v[j][d]; thread: i = tid>>2, 8 d's
        const int i = tid >> 2;
        const int d0 = (tid & 3) * 8;
        float acc[8] = {0, 0, 0, 0, 0, 0, 0, 0};
        for (int j = 0; j < NPG; ++j) {
            const float p = sc[i][j];
            #pragma unroll
            for (int dd = 0; dd < 8; ++dd) acc[dd] += p * vs[j][d0 + dd];
        }
        float* dst = attn_out + (size_t)(g * NPG + i) * HIDDEN + h * HEADDIM + d0;
        *(float4*)(dst)     = make_float4(acc[0], acc[1], acc[2], acc[3]);
        *(float4*)(dst + 4) = make_float4(acc[4], acc[5], acc[6], acc[7]);
    }
}

// ---------------------------------------------------------------------------
extern "C" void kernel_launch(void* const* d_in, const int* in_sizes, int n_in,
                              void* d_out, int out_size, void* d_ws, size_t ws_size,
                              hipStream_t stream)
{
    const float* nodes     = (const float*)d_in[0];
    const float* edges     = (const float*)d_in[1];
    // d_in[2] = n_node (constant 64 per graph; structure hardcoded)
    const int*   senders   = (const int*)d_in[3];
    const int*   receivers = (const int*)d_in[4];
    const float* Wq = (const float*)d_in[5];
    const float* bq = (const float*)d_in[6];
    const float* Wk = (const float*)d_in[7];
    const float* bk = (const float*)d_in[8];
    const float* Wv = (const float*)d_in[9];
    const float* bv = (const float*)d_in[10];
    const float* Wo = (const float*)d_in[11];
    const float* bo = (const float*)d_in[12];
    const float* We = (const float*)d_in[13];
    const float* be = (const float*)d_in[14];
    float* out = (float*)d_out;

    // Workspace: q, k, v fp32 [2048][256] each (6 MB total).
    float* q = (float*)d_ws;
    float* k = q + (size_t)N_NODES * HIDDEN;
    float* v = k + (size_t)N_NODES * HIDDEN;

    dim3 blk(256);
    dim3 gemm_grid(HIDDEN / 64, N_NODES / 64);  // (4, 32)

    gemm_f32_kernel<<<gemm_grid, blk, 0, stream>>>(nodes, Wq, bq, q,
                                                   N_NODES, HIDDEN, HIDDEN);
    gemm_f32_kernel<<<gemm_grid, blk, 0, stream>>>(nodes, Wk, bk, k,
                                                   N_NODES, HIDDEN, HIDDEN);
    gemm_f32_kernel<<<gemm_grid, blk, 0, stream>>>(nodes, Wv, bv, v,
                                                   N_NODES, HIDDEN, HIDDEN);
    attn_f32_kernel<<<dim3(N_GRAPHS, NHEADS), blk, 0, stream>>>(
        q, k, v, edges, We, be, senders, receivers, q /* overwrite Q slot */);
    gemm_f32_kernel<<<gemm_grid, blk, 0, stream>>>(q, Wo, bo, out,
                                                   N_NODES, HIDDEN, HIDDEN);
}

// Round 3
// 117.232 us; speedup vs baseline: 1.3403x; 1.3403x over previous
//
#include <hip/hip_runtime.h>

// Problem constants (fixed by setup_inputs)
#define N_NODES 2048
#define N_GRAPHS 32
#define NPG 64
#define N_EDGES 16384
#define EPG 512          // edges per graph (graph-major ordering)
#define HIDDEN 256
#define NHEADS 8
#define HEADDIM 32
#define EDGEFEAT 16
#define ATT_SCALE 0.17677669529663687f  // 32^-0.5

// GEMM tile config
#define BM 32
#define BN 64
#define BK 32
#define NT (HIDDEN / BK)   // 8 k-tiles

// ---------------------------------------------------------------------------
// Tiled fp32 GEMM v2: C[M,256] = A[M,256] @ W[256,256] + bias.
// BM=32, BN=64, BK=32, 256 threads, 2x4 per thread.
// Register prefetch + LDS double buffer (1 barrier per k-tile).
// blockIdx.z selects one of up to 3 (W, bias, C) triples (fused QKV).
// ---------------------------------------------------------------------------
__global__ __launch_bounds__(256)
void gemm_f32_v2(const float* __restrict__ A,
                 const float* __restrict__ W0, const float* __restrict__ b0, float* __restrict__ C0,
                 const float* __restrict__ W1, const float* __restrict__ b1, float* __restrict__ C1,
                 const float* __restrict__ W2, const float* __restrict__ b2, float* __restrict__ C2)
{
    const int z = blockIdx.z;
    const float* __restrict__ W    = (z == 0) ? W0 : (z == 1) ? W1 : W2;
    const float* __restrict__ bias = (z == 0) ? b0 : (z == 1) ? b1 : b2;
    float* __restrict__ C          = (z == 0) ? C0 : (z == 1) ? C1 : C2;

    __shared__ float As[2][BK][34];  // [buf][k][m] (A transposed), pad 34 (2-way max)
    __shared__ float Bs[2][BK][68];  // [buf][k][n], pad 68 keeps float4 align

    const int tid = threadIdx.x;
    const int m0 = blockIdx.y * BM;
    const int n0 = blockIdx.x * BN;

    // A tile 32x32: 4 floats/thread. r = row (m), ac = k offset
    const int ar = tid >> 3, ac = (tid & 7) * 4;
    // B tile 32x64: 8 floats/thread (rows bk_ and bk_+16)
    const int bk_ = tid >> 4, bn_ = (tid & 15) * 4;

    const float* Aptr = A + (size_t)(m0 + ar) * HIDDEN + ac;
    const float* Wptr0 = W + (size_t)bk_ * HIDDEN + n0 + bn_;
    const float* Wptr1 = W + (size_t)(bk_ + 16) * HIDDEN + n0 + bn_;

    // prefetch tile 0
    float4 aR  = *(const float4*)(Aptr);
    float4 bR0 = *(const float4*)(Wptr0);
    float4 bR1 = *(const float4*)(Wptr1);

    // store tile 0 into buf 0
    As[0][ac + 0][ar] = aR.x;
    As[0][ac + 1][ar] = aR.y;
    As[0][ac + 2][ar] = aR.z;
    As[0][ac + 3][ar] = aR.w;
    *(float4*)&Bs[0][bk_][bn_]      = bR0;
    *(float4*)&Bs[0][bk_ + 16][bn_] = bR1;
    __syncthreads();

    const int tx = tid & 15, ty = tid >> 4;   // tx: 4 n-cols, ty: 2 m-rows
    float acc[2][4] = {};

    for (int t = 0; t < NT; ++t) {
        const int cur = t & 1, nxt = cur ^ 1;
        // issue next-tile global loads (latency hidden under compute)
        if (t + 1 < NT) {
            const size_t k0 = (size_t)(t + 1) * BK;
            aR  = *(const float4*)(Aptr + k0);
            bR0 = *(const float4*)(Wptr0 + k0 * HIDDEN);
            bR1 = *(const float4*)(Wptr1 + k0 * HIDDEN);
        }
        #pragma unroll
        for (int k = 0; k < BK; ++k) {
            float2 a2 = *(const float2*)&As[cur][k][ty * 2];
            float4 b4 = *(const float4*)&Bs[cur][k][tx * 4];
            acc[0][0] += a2.x * b4.x;
            acc[0][1] += a2.x * b4.y;
            acc[0][2] += a2.x * b4.z;
            acc[0][3] += a2.x * b4.w;
            acc[1][0] += a2.y * b4.x;
            acc[1][1] += a2.y * b4.y;
            acc[1][2] += a2.y * b4.z;
            acc[1][3] += a2.y * b4.w;
        }
        if (t + 1 < NT) {
            As[nxt][ac + 0][ar] = aR.x;
            As[nxt][ac + 1][ar] = aR.y;
            As[nxt][ac + 2][ar] = aR.z;
            As[nxt][ac + 3][ar] = aR.w;
            *(float4*)&Bs[nxt][bk_][bn_]      = bR0;
            *(float4*)&Bs[nxt][bk_ + 16][bn_] = bR1;
        }
        __syncthreads();
    }

    float4 bsv = *(const float4*)(bias + n0 + tx * 4);
    #pragma unroll
    for (int i = 0; i < 2; ++i) {
        const int m = m0 + ty * 2 + i;
        float4 o;
        o.x = acc[i][0] + bsv.x;
        o.y = acc[i][1] + bsv.y;
        o.z = acc[i][2] + bsv.z;
        o.w = acc[i][3] + bsv.w;
        *(float4*)(C + (size_t)m * HIDDEN + n0 + tx * 4) = o;
    }
}

// ---------------------------------------------------------------------------
// Fused block-diagonal attention, one block per (graph, head), fp32.
// scores + inline edge bias (unique (r,s) per graph => race-free scatter)
// + softmax (4 threads per row) + AV. Output overwrites Q workspace slot:
// block (g,h) touches only rows g*64.., cols h*32.. — disjoint across blocks.
// ---------------------------------------------------------------------------
__global__ __launch_bounds__(256)
void attn_f32_kernel(const float* __restrict__ q,      // [2048][256]
                     const float* __restrict__ k,
                     const float* __restrict__ v,
                     const float* __restrict__ edges,  // [16384][16]
                     const float* __restrict__ We,     // [16][8]
                     const float* __restrict__ be,     // [8]
                     const int* __restrict__ senders,
                     const int* __restrict__ receivers,
                     float* __restrict__ attn_out)     // aliases q (safe)
{
    const int g = blockIdx.x;
    const int h = blockIdx.y;
    const int tid = threadIdx.x;

    __shared__ float qs[NPG][HEADDIM + 1];
    __shared__ float ks[NPG][HEADDIM + 1];
    __shared__ float vs[NPG][HEADDIM + 1];
    __shared__ float sc[NPG][NPG + 1];
    __shared__ float red_m[4][NPG];
    __shared__ float red_s[4][NPG];
    __shared__ float we_h[EDGEFEAT];
    __shared__ float sbe;

    if (tid < EDGEFEAT) we_h[tid] = We[tid * NHEADS + h];
    if (tid == 0) sbe = be[h];

    {   // load q,k,v head slices: 8 floats (2x float4) per thread per tensor
        const int row = tid >> 2;
        const int c8  = (tid & 3) * 8;
        const size_t base = (size_t)(g * NPG + row) * HIDDEN + h * HEADDIM + c8;
        *(float4*)&qs[row][c8]     = *(const float4*)(q + base);
        *(float4*)&qs[row][c8 + 4] = *(const float4*)(q + base + 4);
        *(float4*)&ks[row][c8]     = *(const float4*)(k + base);
        *(float4*)&ks[row][c8 + 4] = *(const float4*)(k + base + 4);
        *(float4*)&vs[row][c8]     = *(const float4*)(v + base);
        *(float4*)&vs[row][c8 + 4] = *(const float4*)(v + base + 4);
    }
    __syncthreads();

    const int i  = tid & 63;   // row
    const int q4 = tid >> 6;   // quarter: 16 j's each

    {   // scores
        float qr[HEADDIM];
        #pragma unroll
        for (int d = 0; d < HEADDIM; ++d) qr[d] = qs[i][d];
        #pragma unroll
        for (int jj = 0; jj < 16; ++jj) {
            const int j = q4 * 16 + jj;
            float acc = 0.f;
            #pragma unroll
            for (int d = 0; d < HEADDIM; ++d) acc += qr[d] * ks[j][d];
            sc[i][j] = acc * ATT_SCALE;
        }
    }
    __syncthreads();

    {   // edge bias: 512 edges/graph, 2 per thread, unique (r,s) -> race-free
        #pragma unroll
        for (int rep = 0; rep < 2; ++rep) {
            const int e = g * EPG + rep * 256 + tid;
            const float* ef = edges + (size_t)e * EDGEFEAT;
            float4 f0 = *(const float4*)(ef + 0);
            float4 f1 = *(const float4*)(ef + 4);
            float4 f2 = *(const float4*)(ef + 8);
            float4 f3 = *(const float4*)(ef + 12);
            float b = sbe
                + f0.x * we_h[0]  + f0.y * we_h[1]  + f0.z * we_h[2]  + f0.w * we_h[3]
                + f1.x * we_h[4]  + f1.y * we_h[5]  + f1.z * we_h[6]  + f1.w * we_h[7]
                + f2.x * we_h[8]  + f2.y * we_h[9]  + f2.z * we_h[10] + f2.w * we_h[11]
                + f3.x * we_h[12] + f3.y * we_h[13] + f3.z * we_h[14] + f3.w * we_h[15];
            const int s_l = senders[e] & (NPG - 1);
            const int r_l = receivers[e] & (NPG - 1);
            sc[r_l][s_l] += b;
        }
    }
    __syncthreads();

    {   // softmax over j, 4 threads per row
        float m = -1e30f;
        #pragma unroll
        for (int jj = 0; jj < 16; ++jj) m = fmaxf(m, sc[i][q4 * 16 + jj]);
        red_m[q4][i] = m;
        __syncthreads();
        m = fmaxf(fmaxf(red_m[0][i], red_m[1][i]), fmaxf(red_m[2][i], red_m[3][i]));
        float s = 0.f;
        #pragma unroll
        for (int jj = 0; jj < 16; ++jj) {
            const int j = q4 * 16 + jj;
            float e = __expf(sc[i][j] - m);
            sc[i][j] = e;
            s += e;
        }
        red_s[q4][i] = s;
        __syncthreads();
        const float inv = 1.f / (red_s[0][i] + red_s[1][i] + red_s[2][i] + red_s[3][i]);
        #pragma unroll
        for (int jj = 0; jj < 16; ++jj) sc[i][q4 * 16 + jj] *= inv;
    }
    __syncthreads();

    {   // out[i][d] = sum_j p[i][j] * v[j][d]; thread: row = tid>>2, 8 d's
        const int row = tid >> 2;
        const int d0 = (tid & 3) * 8;
        float acc[8] = {0, 0, 0, 0, 0, 0, 0, 0};
        for (int j = 0; j < NPG; ++j) {
            const float p = sc[row][j];
            #pragma unroll
            for (int dd = 0; dd < 8; ++dd) acc[dd] += p * vs[j][d0 + dd];
        }
        float* dst = attn_out + (size_t)(g * NPG + row) * HIDDEN + h * HEADDIM + d0;
        *(float4*)(dst)     = make_float4(acc[0], acc[1], acc[2], acc[3]);
        *(float4*)(dst + 4) = make_float4(acc[4], acc[5], acc[6], acc[7]);
    }
}

// ---------------------------------------------------------------------------
extern "C" void kernel_launch(void* const* d_in, const int* in_sizes, int n_in,
                              void* d_out, int out_size, void* d_ws, size_t ws_size,
                              hipStream_t stream)
{
    const float* nodes     = (const float*)d_in[0];
    const float* edges     = (const float*)d_in[1];
    // d_in[2] = n_node (constant 64 per graph; structure hardcoded)
    const int*   senders   = (const int*)d_in[3];
    const int*   receivers = (const int*)d_in[4];
    const float* Wq = (const float*)d_in[5];
    const float* bq = (const float*)d_in[6];
    const float* Wk = (const float*)d_in[7];
    const float* bk = (const float*)d_in[8];
    const float* Wv = (const float*)d_in[9];
    const float* bv = (const float*)d_in[10];
    const float* Wo = (const float*)d_in[11];
    const float* bo = (const float*)d_in[12];
    const float* We = (const float*)d_in[13];
    const float* be = (const float*)d_in[14];
    float* out = (float*)d_out;

    // Workspace: q, k, v fp32 [2048][256] each (6 MB total).
    float* q = (float*)d_ws;
    float* k = q + (size_t)N_NODES * HIDDEN;
    float* v = k + (size_t)N_NODES * HIDDEN;

    dim3 blk(256);

    // Fused QKV: 4 x 64 x 3 = 768 blocks
    gemm_f32_v2<<<dim3(HIDDEN / BN, N_NODES / BM, 3), blk, 0, stream>>>(
        nodes, Wq, bq, q, Wk, bk, k, Wv, bv, v);

    // Attention: 256 blocks
    attn_f32_kernel<<<dim3(N_GRAPHS, NHEADS), blk, 0, stream>>>(
        q, k, v, edges, We, be, senders, receivers, q /* overwrite Q slot */);

    // Output projection: 4 x 64 = 256 blocks
    gemm_f32_v2<<<dim3(HIDDEN / BN, N_NODES / BM, 1), blk, 0, stream>>>(
        q, Wo, bo, out, Wo, bo, out, Wo, bo, out);
}